// Round 5
// baseline (466.556 us; speedup 1.0000x reference)
//
#include <hip/hip_runtime.h>
#include <hip/hip_bf16.h>

// ---------- types ----------
typedef unsigned short u16;
typedef __attribute__((ext_vector_type(4))) float f32x4;
typedef __attribute__((ext_vector_type(8))) short short8;   // 8 bf16 for MFMA operands
typedef __attribute__((ext_vector_type(8))) u16 u16x8;

__device__ __forceinline__ f32x4 fzero() { f32x4 z = {0.f, 0.f, 0.f, 0.f}; return z; }

// f32 -> bf16 bits, round-to-nearest-even
__device__ __forceinline__ u16 f2b(float x) {
  unsigned u = __builtin_bit_cast(unsigned, x);
  unsigned r = (u + 0x7fffu + ((u >> 16) & 1u)) >> 16;
  return (u16)r;
}

// ---------- problem constants ----------
#define BS 4096
#define A_ 30

// ---------- ws offsets (bytes) ----------
#define OFF_W2B   0UL            // 33,685,504  (2056 slices x 16KB, frag-order)
#define OFF_H1B   33685504UL     //  2,097,152
#define OFF_XIN   35782656UL     //  4,194,304
#define OFF_WCFR  39976960UL     //    393,216  (Wc = wih@few, frag-order)
#define OFF_WHFR  40370176UL     //    393,216  (whh, frag-order)
#define OFF_BC    40763392UL     //      3,072  (bc = bih + wih@feb)
#define OFF_PART  40766464UL     // 33,554,432
// end 74,320,896

#define NB_W2   8224
#define NB_WHH  96
#define NB_LN1  4096
#define NB_H1   4096
#define NB_WC   768
#define NB_PRE  (NB_W2 + NB_WHH + NB_LN1 + NB_H1 + NB_WC)   // 17280

// ================= block-wide mean/inv-std over 256 elems (256 thr) =================
__device__ __forceinline__ void blk_ln(float v, float* red, int t, float& mu, float& inv) {
  float s = v, sq = v * v;
  #pragma unroll
  for (int o = 32; o; o >>= 1) { s += __shfl_xor(s, o); sq += __shfl_xor(sq, o); }
  int w = t >> 6;
  if ((t & 63) == 0) { red[w] = s; red[4 + w] = sq; }
  __syncthreads();
  float S = red[0] + red[1] + red[2] + red[3];
  float Q = red[4] + red[5] + red[6] + red[7];
  mu = S * (1.f / 256.f);
  float var = Q * (1.f / 256.f) - mu * mu;
  inv = rsqrtf(var + 1e-5f);
  __syncthreads();
}

// ================= k_pre: conversions + ln1 + h1 + Wc/bc =================
// w2b frag layout: dst[((i*8+ks)*256 + h)*32 + kk] = hy_w2[i*256+h][ks*32+kk]
// whfr/wcfr frag layout: dst[(ks*768 + g)*32 + kk] = W[g][ks*32+kk]
__global__ void k_pre(const float* __restrict__ hyw2, const float* __restrict__ whh,
                      const float* __restrict__ inp,  const float* __restrict__ ln1g,
                      const float* __restrict__ ln1b,
                      const float* __restrict__ goal, const float* __restrict__ hyw1,
                      const float* __restrict__ hyb1,
                      const float* __restrict__ wih,  const float* __restrict__ few,
                      const float* __restrict__ feb,  const float* __restrict__ bih,
                      u16* __restrict__ w2b, u16* __restrict__ whfr,
                      float* __restrict__ xin, u16* __restrict__ h1b,
                      u16* __restrict__ wcfr, float* __restrict__ bcv) {
  const int bx = blockIdx.x, t = threadIdx.x;
  __shared__ float sm[256];
  __shared__ float red[8];

  if (bx < NB_W2) {                       // ---- w2 -> bf16 frag slices ----
    long c = (long)bx * 256 + t;
    long d = c * 8;
    int kk0 = (int)((c & 3) * 8);
    int h   = (int)((c >> 2) & 255);
    long s  = c >> 10;                    // slice 0..2055
    int ks  = (int)(s & 7);
    long i  = s >> 3;                     // 0..256 (i==256 -> bias rows)
    const float* src = hyw2 + (i * 256 + h) * 256 + ks * 32 + kk0;
    f32x4 a = *(const f32x4*)src;
    f32x4 b = *(const f32x4*)(src + 4);
    u16x8 o;
    o[0]=f2b(a[0]); o[1]=f2b(a[1]); o[2]=f2b(a[2]); o[3]=f2b(a[3]);
    o[4]=f2b(b[0]); o[5]=f2b(b[1]); o[6]=f2b(b[2]); o[7]=f2b(b[3]);
    *(u16x8*)(w2b + d) = o;
    return;
  }
  if (bx < NB_W2 + NB_WHH) {              // ---- whh -> bf16 frag layout ----
    int c = (bx - NB_W2) * 256 + t;       // 0..24575
    int ks = c / 3072, rem = c - ks * 3072;
    int g = rem >> 2, kk0 = (rem & 3) * 8;
    const float* src = whh + (long)g * 256 + ks * 32 + kk0;
    f32x4 a = *(const f32x4*)src;
    f32x4 b = *(const f32x4*)(src + 4);
    u16x8 o;
    o[0]=f2b(a[0]); o[1]=f2b(a[1]); o[2]=f2b(a[2]); o[3]=f2b(a[3]);
    o[4]=f2b(b[0]); o[5]=f2b(b[1]); o[6]=f2b(b[2]); o[7]=f2b(b[3]);
    *(u16x8*)(whfr + ((long)ks * 768 + g) * 32 + kk0) = o;
    return;
  }
  if (bx < NB_W2 + NB_WHH + NB_LN1) {     // ---- ln1 ----
    int bb = bx - (NB_W2 + NB_WHH);
    float v = inp[(long)bb * 256 + t];
    float mu, inv; blk_ln(v, red, t, mu, inv);
    xin[(long)bb * 256 + t] = (v - mu) * inv * ln1g[t] + ln1b[t];
    return;
  }
  if (bx < NB_W2 + NB_WHH + NB_LN1 + NB_H1) {   // ---- h1 ----
    int bb = bx - (NB_W2 + NB_WHH + NB_LN1);
    if (t < 64) sm[t] = goal[(long)bb * 64 + t];
    __syncthreads();
    const float* wr = hyw1 + (long)t * 64;
    float acc = hyb1[t];
    #pragma unroll
    for (int g4 = 0; g4 < 16; ++g4) {
      f32x4 w = *(const f32x4*)(wr + g4 * 4);
      acc = fmaf(sm[g4*4+0], w[0], acc);
      acc = fmaf(sm[g4*4+1], w[1], acc);
      acc = fmaf(sm[g4*4+2], w[2], acc);
      acc = fmaf(sm[g4*4+3], w[3], acc);
    }
    h1b[(long)bb * 256 + t] = f2b(fmaxf(acc, 0.f));
    return;
  }
  {                                       // ---- Wc row gg (frag layout) + bc[gg] ----
    int gg = bx - (NB_W2 + NB_WHH + NB_LN1 + NB_H1);
    sm[t] = wih[(long)gg * 256 + t];
    __syncthreads();
    float acc = 0.f;
    #pragma unroll 8
    for (int e = 0; e < 256; ++e) acc = fmaf(sm[e], few[(long)e * 256 + t], acc);
    wcfr[((long)(t >> 5) * 768 + gg) * 32 + (t & 31)] = f2b(acc);
    // bc[gg] = bih[gg] + wih[gg,:]·feb
    float p = sm[t] * feb[t];
    #pragma unroll
    for (int o = 32; o; o >>= 1) p += __shfl_xor(p, o);
    if ((t & 63) == 0) red[t >> 6] = p;
    __syncthreads();
    if (t == 0) bcv[gg] = bih[gg] + red[0] + red[1] + red[2] + red[3];
  }
}

// ================= k_big: fused hypernet GEMM + tanh*3 + contraction ==========
// grid 512 = 64 btiles x 8 islices (islice = bx&7 -> XCD-pinned 4.2MB w2 chunk).
// 8 waves/block (2 wr x 4 wc), 512 thr, launch_bounds(512,4) -> 4 waves/SIMD (TLP).
// B streams global->VGPR (frag-order, coalesced), 2-deep parity register ring.
// Per-ii rhythm barrier (no vmcnt drain); NT part stores keep w2 resident in L2.
__global__ __launch_bounds__(512, 4) void k_big(const u16* __restrict__ w2b,
                                                const u16* __restrict__ h1b,
                                                const float* __restrict__ xin,
                                                const float* __restrict__ b2,
                                                float* __restrict__ part) {
  const int bx = blockIdx.x;
  const int islice = bx & 7, btile = bx >> 3;
  const int b0 = btile * 64, i0 = islice * 32;
  const int ni = (islice == 7) ? 33 : 32;   // islice 7 adds the bias row-block (i==256)
  const int t = threadIdx.x, lane = t & 63, wid = t >> 6;
  const int la = lane & 15, lb = lane >> 4;
  const int wr = wid >> 2, wc = wid & 3;
  const int r0 = wr * 32, c0 = wc * 64;

  __shared__ u16 As[64 * 264];      // h1 tile, pitch 264 (2-way bank spread = free)
  __shared__ float xs[32][64];      // xin slice [ii][row]

  #pragma unroll
  for (int j = 0; j < 4; ++j) {
    int q = t + 512 * j;
    int row = q >> 5, cc = q & 31;
    *(u16x8*)&As[row * 264 + cc * 8] = *(const u16x8*)(h1b + (long)(b0 + row) * 256 + cc * 8);
  }
  {
    int row = t >> 3, p4 = t & 7;
    const float* src = xin + (long)(b0 + row) * 256 + i0 + p4 * 4;
    f32x4 v = *(const f32x4*)src;
    #pragma unroll
    for (int j = 0; j < 4; ++j) xs[p4 * 4 + j][row] = v[j];
  }
  __syncthreads();

  const u16* bptr = w2b + (long)i0 * 8 * 8192 + (c0 + la) * 32 + lb * 8;
  const int lds_a = (r0 + la) * 528 + lb * 16;   // byte offset into As

  f32x4 accT[2][4];
  #pragma unroll
  for (int m = 0; m < 2; ++m)
    #pragma unroll
    for (int n = 0; n < 4; ++n) accT[m][n] = fzero();

  short8 bf[2][4];   // [parity][n] — 2-deep register prefetch ring
  #pragma unroll
  for (int s = 0; s < 2; ++s)
    #pragma unroll
    for (int n = 0; n < 4; ++n)
      bf[s][n] = *(const short8*)(bptr + (long)s * 8192 + n * 512);

  for (int ii = 0; ii < ni; ++ii) {
    __builtin_amdgcn_s_barrier();   // per-ii rhythm barrier (no vmcnt drain)
    f32x4 cf[2][4];
    #pragma unroll
    for (int ks = 0; ks < 8; ++ks) {
      const int s = ii * 8 + ks;
      short8 af[2];
      #pragma unroll
      for (int m = 0; m < 2; ++m)
        af[m] = *(const short8*)((const char*)As + lds_a + m * 8448 + ks * 64);
      __builtin_amdgcn_s_setprio(1);
      if (ks == 0) {
        #pragma unroll
        for (int m = 0; m < 2; ++m)
          #pragma unroll
          for (int n = 0; n < 4; ++n)
            cf[m][n] = __builtin_amdgcn_mfma_f32_16x16x32_bf16(af[m], bf[ks & 1][n], fzero(), 0, 0, 0);
      } else {
        #pragma unroll
        for (int m = 0; m < 2; ++m)
          #pragma unroll
          for (int n = 0; n < 4; ++n)
            cf[m][n] = __builtin_amdgcn_mfma_f32_16x16x32_bf16(af[m], bf[ks & 1][n], cf[m][n], 0, 0, 0);
      }
      __builtin_amdgcn_s_setprio(0);
      // prefetch slice s+2 into the parity slot just consumed (over-reads stay in ws)
      #pragma unroll
      for (int n = 0; n < 4; ++n)
        bf[ks & 1][n] = *(const short8*)(bptr + (long)(s + 2) * 8192 + n * 512);
    }
    // epilogue (loads placed late to shrink ks-loop live ranges):
    const int ig = i0 + ii;
    const bool isb = (ig == 256);
    f32x4 xv[2];
    if (isb) {
      #pragma unroll
      for (int m = 0; m < 2; ++m) { f32x4 o = {1.f,1.f,1.f,1.f}; xv[m] = o; }
    } else {
      #pragma unroll
      for (int m = 0; m < 2; ++m)
        xv[m] = *(const f32x4*)&xs[ii][r0 + m * 16 + lb * 4];
    }
    float b2v[4];
    #pragma unroll
    for (int n = 0; n < 4; ++n)
      b2v[n] = b2[(long)ig * 256 + c0 + n * 16 + la];
    #pragma unroll
    for (int m = 0; m < 2; ++m)
      #pragma unroll
      for (int n = 0; n < 4; ++n)
        #pragma unroll
        for (int r = 0; r < 4; ++r) {
          float pre = cf[m][n][r] + b2v[n];
          float t2 = pre * pre;
          float w = pre * fmaf(t2, fmaf(t2, fmaf(t2, -0.161905f, 0.4f), -1.0f), 3.0f);
          accT[m][n][r] = fmaf(xv[m][r], w, accT[m][n][r]);
        }
  }

  // non-temporal C-write: keep the 32MB 'part' stream out of the XCD L2
  float* dst = part + (long)islice * (4096 * 256);
  #pragma unroll
  for (int m = 0; m < 2; ++m)
    #pragma unroll
    for (int n = 0; n < 4; ++n)
      #pragma unroll
      for (int r = 0; r < 4; ++r)
        __builtin_nontemporal_store(accT[m][n][r],
            &dst[(long)(b0 + r0 + m * 16 + lb * 4 + r) * 256 + (c0 + n * 16 + la)]);
}

// ================= k_post: redln + (gi,gh) MFMA + GRU + dueling heads ==========
// 256 blocks x 16 rows, 512 thr (8 waves -> 2/SIMD). yb lives only in LDS.
__global__ __launch_bounds__(512) void k_post(const float* __restrict__ part,
                                              const float* __restrict__ ln2g,
                                              const float* __restrict__ ln2b,
                                              const u16* __restrict__ wcfr,
                                              const u16* __restrict__ whfr,
                                              const float* __restrict__ bcv,
                                              const float* __restrict__ bhh,
                                              const float* __restrict__ hidden,
                                              const float* __restrict__ advw,
                                              const float* __restrict__ advb,
                                              const float* __restrict__ valw,
                                              const float* __restrict__ valb,
                                              float* __restrict__ qout,
                                              float* __restrict__ hout) {
  const int bx = blockIdx.x, t = threadIdx.x;
  const int b0 = bx * 16;
  __shared__ u16 ya[16 * 264];     // relu(LN2) tile, A-frag friendly
  __shared__ u16 ha[16 * 264];     // hidden bf16 tile
  __shared__ float hs[16 * 264];   // h (f32) for heads
  __shared__ float ov[16][33];
  __shared__ float ms[16];

  // ---- phase 1: redln -> ya ; hidden -> ha ----
  {
    const int r = t >> 5, ch = (t & 31) * 8;
    const float* pb = part + (long)(b0 + r) * 256 + ch;
    f32x4 s0 = fzero(), s1 = fzero();
    #pragma unroll
    for (int sl = 0; sl < 8; ++sl) {
      const f32x4* ps = (const f32x4*)(pb + (long)sl * (4096 * 256));
      s0 += __builtin_nontemporal_load(ps);
      s1 += __builtin_nontemporal_load(ps + 1);
    }
    float sv = 0.f, sq = 0.f;
    #pragma unroll
    for (int j = 0; j < 4; ++j) { sv += s0[j] + s1[j]; sq += s0[j]*s0[j] + s1[j]*s1[j]; }
    #pragma unroll
    for (int o = 1; o < 32; o <<= 1) { sv += __shfl_xor(sv, o); sq += __shfl_xor(sq, o); }
    float mu = sv * (1.f / 256.f);
    float inv = rsqrtf(sq * (1.f / 256.f) - mu * mu + 1e-5f);
    u16x8 o8;
    #pragma unroll
    for (int j = 0; j < 4; ++j) {
      float v0 = (s0[j] - mu) * inv * ln2g[ch + j] + ln2b[ch + j];
      float v1 = (s1[j] - mu) * inv * ln2g[ch + 4 + j] + ln2b[ch + 4 + j];
      o8[j]     = f2b(fmaxf(v0, 0.f));
      o8[4 + j] = f2b(fmaxf(v1, 0.f));
    }
    *(u16x8*)&ya[r * 264 + ch] = o8;
    const float* hp = hidden + (long)(b0 + r) * 256 + ch;
    u16x8 oh;
    #pragma unroll
    for (int j = 0; j < 8; ++j) oh[j] = f2b(hp[j]);
    *(u16x8*)&ha[r * 264 + ch] = oh;
  }
  __syncthreads();

  // ---- phase 2: GEMM (gi+gh fused into gates) ----
  const int lane = t & 63, wid = t >> 6;
  const int la = lane & 15, lb = lane >> 4;
  const int c0w = wid * 32;
  f32x4 aR[2], aZ[2], aN[2], aH[2];
  #pragma unroll
  for (int n = 0; n < 2; ++n) { aR[n] = fzero(); aZ[n] = fzero(); aN[n] = fzero(); aH[n] = fzero(); }
  #pragma unroll
  for (int ks = 0; ks < 8; ++ks) {
    short8 ay = *(const short8*)&ya[la * 264 + ks * 32 + lb * 8];
    short8 ah = *(const short8*)&ha[la * 264 + ks * 32 + lb * 8];
    #pragma unroll
    for (int n = 0; n < 2; ++n) {
      const int c = c0w + n * 16 + la;
      const u16* wp = wcfr + ((long)ks * 768 + c) * 32 + lb * 8;
      const u16* hp = whfr + ((long)ks * 768 + c) * 32 + lb * 8;
      short8 bWr = *(const short8*)wp;
      short8 bWz = *(const short8*)(wp + 256 * 32);
      short8 bWn = *(const short8*)(wp + 512 * 32);
      short8 bHr = *(const short8*)hp;
      short8 bHz = *(const short8*)(hp + 256 * 32);
      short8 bHn = *(const short8*)(hp + 512 * 32);
      aR[n] = __builtin_amdgcn_mfma_f32_16x16x32_bf16(ay, bWr, aR[n], 0, 0, 0);
      aR[n] = __builtin_amdgcn_mfma_f32_16x16x32_bf16(ah, bHr, aR[n], 0, 0, 0);
      aZ[n] = __builtin_amdgcn_mfma_f32_16x16x32_bf16(ay, bWz, aZ[n], 0, 0, 0);
      aZ[n] = __builtin_amdgcn_mfma_f32_16x16x32_bf16(ah, bHz, aZ[n], 0, 0, 0);
      aN[n] = __builtin_amdgcn_mfma_f32_16x16x32_bf16(ay, bWn, aN[n], 0, 0, 0);
      aH[n] = __builtin_amdgcn_mfma_f32_16x16x32_bf16(ah, bHn, aH[n], 0, 0, 0);
    }
  }

  // ---- phase 3: GRU elementwise ----
  #pragma unroll
  for (int n = 0; n < 2; ++n) {
    const int c = c0w + n * 16 + la;
    float bcr = bcv[c], bcz = bcv[c + 256], bcn = bcv[c + 512];
    float bhr = bhh[c], bhz = bhh[c + 256], bhn = bhh[c + 512];
    #pragma unroll
    for (int jr = 0; jr < 4; ++jr) {
      const int row = lb * 4 + jr;
      const long gb = (long)(b0 + row) * 256 + c;
      float rr = 1.f / (1.f + expf(-(aR[n][jr] + bcr + bhr)));
      float zz = 1.f / (1.f + expf(-(aZ[n][jr] + bcz + bhz)));
      float nn = tanhf(aN[n][jr] + bcn + rr * (aH[n][jr] + bhn));
      float hp = hidden[gb];
      float h = (1.f - zz) * nn + zz * hp;
      hout[gb] = h;
      hs[row * 264 + c] = h;
    }
  }
  __syncthreads();

  // ---- phase 4: dueling heads ----
  {
    const int out = t >> 4, lg = t & 15;          // 32 out-groups x 16 lanes
    if (out < 31) {
      const float* wr2 = (out < 30) ? (advw + (long)out * 256) : valw;
      for (int r = 0; r < 16; ++r) {
        float p = 0.f;
        #pragma unroll 8
        for (int j = 0; j < 16; ++j) p += hs[r * 264 + lg + 16 * j] * wr2[lg + 16 * j];
        p += __shfl_xor(p, 1); p += __shfl_xor(p, 2);
        p += __shfl_xor(p, 4); p += __shfl_xor(p, 8);
        if (lg == 0) ov[r][out] = p + ((out < 30) ? advb[out] : valb[0]);
      }
    }
  }
  __syncthreads();
  if (t < 16) {
    float m = 0.f;
    #pragma unroll
    for (int a = 0; a < 30; ++a) m += ov[t][a];
    ms[t] = m * (1.f / 30.f);
  }
  __syncthreads();
  {
    const int r = t >> 5, o = t & 31;
    if (o < 30) qout[(long)(b0 + r) * 30 + o] = ov[r][30] + ov[r][o] - ms[r];
  }
}

// ================= launch =================
extern "C" void kernel_launch(void* const* d_in, const int* in_sizes, int n_in,
                              void* d_out, int out_size, void* d_ws, size_t ws_size,
                              hipStream_t stream) {
  const float* inputs = (const float*)d_in[0];
  const float* hidden = (const float*)d_in[1];
  const float* goal   = (const float*)d_in[2];
  const float* ln1g   = (const float*)d_in[3];
  const float* ln1b   = (const float*)d_in[4];
  const float* hyw1   = (const float*)d_in[5];
  const float* hyb1   = (const float*)d_in[6];
  const float* hyw2   = (const float*)d_in[7];
  const float* hyb2   = (const float*)d_in[8];
  const float* ln2g   = (const float*)d_in[9];
  const float* ln2b   = (const float*)d_in[10];
  const float* few    = (const float*)d_in[11];
  const float* feb    = (const float*)d_in[12];
  const float* wih    = (const float*)d_in[13];
  const float* whh    = (const float*)d_in[14];
  const float* bih    = (const float*)d_in[15];
  const float* bhh    = (const float*)d_in[16];
  const float* valw   = (const float*)d_in[17];
  const float* valb   = (const float*)d_in[18];
  const float* advw   = (const float*)d_in[19];
  const float* advb   = (const float*)d_in[20];

  char* ws = (char*)d_ws;
  u16* w2b    = (u16*)(ws + OFF_W2B);
  u16* h1b    = (u16*)(ws + OFF_H1B);
  float* xin  = (float*)(ws + OFF_XIN);
  u16* wcfr   = (u16*)(ws + OFF_WCFR);
  u16* whfr   = (u16*)(ws + OFF_WHFR);
  float* bcv  = (float*)(ws + OFF_BC);
  float* prt  = (float*)(ws + OFF_PART);
  float* qout = (float*)d_out;
  float* hout = qout + (long)BS * A_;

  k_pre<<<NB_PRE, 256, 0, stream>>>(hyw2, whh, inputs, ln1g, ln1b, goal, hyw1, hyb1,
                                    wih, few, feb, bih,
                                    w2b, whfr, xin, h1b, wcfr, bcv);
  k_big<<<512, 512, 0, stream>>>(w2b, h1b, xin, hyb2, prt);
  k_post<<<256, 512, 0, stream>>>(prt, ln2g, ln2b, wcfr, whfr, bcv, bhh, hidden,
                                  advw, advb, valw, valb, qout, hout);
}